// Round 12
// baseline (58.938 us; speedup 1.0000x reference)
//
#include <hip/hip_runtime.h>

#define N_NODES 50000
#define N_EDGES 640000
#define D 128
#define NBKT 782            // ceil(50000/64) buckets of 64 dst nodes
#define EPB 2048            // edges per scatter block
#define NSB ((N_EDGES + EPB - 1) / EPB)   // 313 scatter blocks
#define GB 196              // gemm super-blocks (4 x 64-row tiles each)
#define CAP 2048            // fixed slot size per bucket (mean 819)

typedef __attribute__((ext_vector_type(8))) short bf16x8;
typedef __attribute__((ext_vector_type(4))) float f32x4;

// round-to-nearest-even f32 -> bf16
static __device__ __forceinline__ unsigned short f2bf(float f) {
    union { float f; unsigned u; } v; v.f = f;
    unsigned r = (v.u + 0x7FFFu + ((v.u >> 16) & 1u)) >> 16;
    return (unsigned short)r;
}

// accumulate 8 bf16 lanes of a uint4 row into acc[8] with weight wt
static __device__ __forceinline__ void acc8(float* A, float wt, uint4 v) {
    A[0] += wt * __uint_as_float(v.x << 16);
    A[1] += wt * __uint_as_float(v.x & 0xFFFF0000u);
    A[2] += wt * __uint_as_float(v.y << 16);
    A[3] += wt * __uint_as_float(v.y & 0xFFFF0000u);
    A[4] += wt * __uint_as_float(v.z << 16);
    A[5] += wt * __uint_as_float(v.z & 0xFFFF0000u);
    A[6] += wt * __uint_as_float(v.w << 16);
    A[7] += wt * __uint_as_float(v.w & 0xFFFF0000u);
}

// ---------------------------------------------------------------------------
// Fused kernel: blocks [0, GB) run the MFMA GEMM (Ybf = bf16(X @ W^T));
// blocks [GB, GB+NSB) run the bucketed edge scatter. (Proven rounds 9-10.)
// ---------------------------------------------------------------------------
__global__ __launch_bounds__(1024) void fused_gemm_scatter(
        const float* __restrict__ X, const float* __restrict__ W,
        const int* __restrict__ src, const int* __restrict__ dst,
        const float* __restrict__ ew,
        unsigned short* __restrict__ Ybf,
        int* __restrict__ bcur, int2* __restrict__ brec) {
    __shared__ __align__(16) char smem[32768];
    const int t = threadIdx.x;

    if (blockIdx.x < GB) {
        // ------------------- GEMM branch (4 tiles of 64 rows) -------------------
        unsigned short (*sB)[4][64][8] = (unsigned short (*)[4][64][8])smem;

        for (int idx = t; idx < 2048; idx += 1024) {
            const int ln = idx & 63;
            const int kk = (idx >> 6) & 3;
            const int ct = idx >> 8;
            const int n  = ct * 16 + (ln & 15);
            const int k0 = kk * 32 + (ln >> 4) * 8;
            const float4 wa = *reinterpret_cast<const float4*>(&W[n * D + k0]);
            const float4 wb = *reinterpret_cast<const float4*>(&W[n * D + k0 + 4]);
            unsigned short* d8 = &sB[ct][kk][ln][0];
            d8[0] = f2bf(wa.x); d8[1] = f2bf(wa.y); d8[2] = f2bf(wa.z); d8[3] = f2bf(wa.w);
            d8[4] = f2bf(wb.x); d8[5] = f2bf(wb.y); d8[6] = f2bf(wb.z); d8[7] = f2bf(wb.w);
        }

        const int s    = t >> 8;            // sub-tile 0..3
        const int wv   = (t >> 6) & 3;      // wave within sub-tile
        const int lane = t & 63;
        const int tile = blockIdx.x * 4 + s;
        const int base = tile * 64;

        const int arow = base + wv * 16 + (lane & 15);
        const int grow = min(arow, N_NODES - 1);
        bf16x8 a[4];
        #pragma unroll
        for (int kk = 0; kk < 4; ++kk) {
            const int k0 = kk * 32 + (lane >> 4) * 8;
            const float4 xa = *reinterpret_cast<const float4*>(&X[(size_t)grow * D + k0]);
            const float4 xb = *reinterpret_cast<const float4*>(&X[(size_t)grow * D + k0 + 4]);
            a[kk][0] = (short)f2bf(xa.x); a[kk][1] = (short)f2bf(xa.y);
            a[kk][2] = (short)f2bf(xa.z); a[kk][3] = (short)f2bf(xa.w);
            a[kk][4] = (short)f2bf(xb.x); a[kk][5] = (short)f2bf(xb.y);
            a[kk][6] = (short)f2bf(xb.z); a[kk][7] = (short)f2bf(xb.w);
        }
        __syncthreads();

        f32x4 acc[8];
        #pragma unroll
        for (int ct = 0; ct < 8; ++ct) acc[ct] = (f32x4){0.f, 0.f, 0.f, 0.f};

        #pragma unroll
        for (int ct = 0; ct < 8; ++ct) {
            #pragma unroll
            for (int kk = 0; kk < 4; ++kk) {
                const bf16x8 b = *reinterpret_cast<const bf16x8*>(&sB[ct][kk][lane][0]);
                acc[ct] = __builtin_amdgcn_mfma_f32_16x16x32_bf16(a[kk], b, acc[ct], 0, 0, 0);
            }
        }

        const int orow0 = base + wv * 16 + (lane >> 4) * 4;
        const int ocol  = lane & 15;
        #pragma unroll
        for (int r = 0; r < 4; ++r) {
            const int row = orow0 + r;
            if (row < N_NODES) {
                #pragma unroll
                for (int ct = 0; ct < 8; ++ct)
                    Ybf[(size_t)row * D + ct * 16 + ocol] = f2bf(acc[ct][r]);
            }
        }
    } else {
        // ------------------- Scatter branch (proven round-7/9/10 body) -------------------
        int*  lcnt   = (int*)(smem);            // 784 ints
        int*  loff   = (int*)(smem + 3136);     // 784 ints
        int*  p      = (int*)(smem + 6272);     // 256 ints
        int*  gbase  = (int*)(smem + 7296);     // NBKT ints
        int*  lcur   = (int*)(smem + 10424);    // NBKT ints
        int2* staged = (int2*)(smem + 13552);   // EPB int2 (16 KB)

        const int base = (blockIdx.x - GB) * EPB;
        const int ec = min(EPB, N_EDGES - base);

        for (int i = t; i < 784; i += 1024) lcnt[i] = 0;
        __syncthreads();

        #pragma unroll
        for (int j = 0; j < EPB / 1024; ++j) {
            const int e = base + j * 1024 + t;
            if (e < N_EDGES) atomicAdd(&lcnt[dst[e] >> 6], 1);
        }
        __syncthreads();

        int s0 = 0;
        if (t < 196) s0 = lcnt[4 * t] + lcnt[4 * t + 1] + lcnt[4 * t + 2] + lcnt[4 * t + 3];
        if (t < 256) p[t] = s0;
        __syncthreads();
        for (int off = 1; off < 256; off <<= 1) {
            int add = 0;
            if (t < 256 && t >= off) add = p[t - off];
            __syncthreads();
            if (t < 256) p[t] += add;
            __syncthreads();
        }
        if (t < 196) {
            int b0 = p[t] - s0;
            #pragma unroll
            for (int k = 0; k < 4; ++k) {
                loff[4 * t + k] = b0;
                b0 += lcnt[4 * t + k];
            }
        }
        __syncthreads();

        for (int b = t; b < NBKT; b += 1024) {
            const int c2 = lcnt[b];
            if (c2 > 0) gbase[b] = (b << 11) + atomicAdd(&bcur[b], c2);
            lcur[b] = loff[b];
        }
        __syncthreads();

        #pragma unroll
        for (int j = 0; j < EPB / 1024; ++j) {
            const int e = base + j * 1024 + t;
            if (e < N_EDGES) {
                const int d = dst[e];
                const int b = d >> 6;
                const int pos = atomicAdd(&lcur[b], 1);
                staged[pos] = make_int2((src[e] & 0xFFFF) | ((d & 63) << 16) | (b << 22),
                                        __float_as_int(ew[e]));
            }
        }
        __syncthreads();

        for (int i = t; i < ec; i += 1024) {
            const int2 r = staged[i];
            const int b = ((unsigned)r.x) >> 22;
            const int idx = gbase[b] + (i - loff[b]);
            if (idx < ((b + 1) << 11)) brec[idx] = r;
        }
    }
}

// ---------------------------------------------------------------------------
// bucket_agg: one block per bucket, 512 threads = 8 waves. Sort phase as
// before (LDS counting sort by dst_local). Gather phase: each wave handles
// node PAIRS (nlA, nlB=nlA+8) with a 2x-unrolled fused loop -> 4 independent
// 16B row gathers in flight per 16-lane group per iteration. Out-of-range
// lanes use clamped indices (always real records of this bucket -> no NaN
// hazard) with weights forced to 0.
// ---------------------------------------------------------------------------
__global__ __launch_bounds__(512) void bucket_agg(const unsigned short* __restrict__ Ybf,
                                                  const int2* __restrict__ brec,
                                                  const int* __restrict__ bcur,
                                                  float* __restrict__ out) {
    __shared__ int  cnts[64];
    __shared__ int  offs[65];
    __shared__ int  cur[64];
    __shared__ int2 sorted[CAP];

    const int t = threadIdx.x;
    const int b = blockIdx.x;
    const int base = b << 11;
    const int cnt = min(bcur[b], CAP);

    if (t < 64) cnts[t] = 0;
    __syncthreads();

    for (int i = t; i < cnt; i += 512)
        atomicAdd(&cnts[(brec[base + i].x >> 16) & 63], 1);
    __syncthreads();

    if (t < 64) {
        int v = cnts[t];
        #pragma unroll
        for (int off = 1; off < 64; off <<= 1) {
            const int u = __shfl_up(v, off, 64);
            if (t >= off) v += u;
        }
        offs[t] = v - cnts[t];
        cur[t]  = v - cnts[t];
        if (t == 63) offs[64] = v;
    }
    __syncthreads();

    for (int i = t; i < cnt; i += 512) {
        const int2 r = brec[base + i];
        const int pos = atomicAdd(&cur[(r.x >> 16) & 63], 1);
        sorted[pos] = r;
    }
    __syncthreads();

    const int wave = t >> 6;          // 0..7
    const int lane = t & 63;
    const int g = lane >> 4;          // edge sub-slot 0..3
    const int c = (lane & 15) * 8;    // 8 output cols

    #pragma unroll
    for (int j = 0; j < 4; ++j) {
        const int nlA = wave + j * 16;
        const int nlB = nlA + 8;
        const int nodeA = b * 64 + nlA;
        const int nodeB = b * 64 + nlB;
        const int a0 = offs[nlA], a1 = offs[nlA + 1];
        const int b0 = offs[nlB], b1 = offs[nlB + 1];

        float accA[8], accB[8];
        #pragma unroll
        for (int k = 0; k < 8; ++k) { accA[k] = 0.f; accB[k] = 0.f; }

        int iA = a0 + g;
        int iB = b0 + g;
        while (iA < a1 || iB < b1) {
            // clamped record indices: always point at real records (no NaN);
            // weights zero any out-of-range contribution
            const int jA0 = max(min(iA,     a1 - 1), 0);
            const int jA1 = max(min(iA + 4, a1 - 1), 0);
            const int jB0 = max(min(iB,     b1 - 1), 0);
            const int jB1 = max(min(iB + 4, b1 - 1), 0);
            const int2 rA0 = sorted[jA0];
            const int2 rA1 = sorted[jA1];
            const int2 rB0 = sorted[jB0];
            const int2 rB1 = sorted[jB1];
            const float wA0 = (iA     < a1) ? __int_as_float(rA0.y) : 0.f;
            const float wA1 = (iA + 4 < a1) ? __int_as_float(rA1.y) : 0.f;
            const float wB0 = (iB     < b1) ? __int_as_float(rB0.y) : 0.f;
            const float wB1 = (iB + 4 < b1) ? __int_as_float(rB1.y) : 0.f;
            const uint4 vA0 = *reinterpret_cast<const uint4*>(&Ybf[(size_t)(rA0.x & 0xFFFF) * D + c]);
            const uint4 vA1 = *reinterpret_cast<const uint4*>(&Ybf[(size_t)(rA1.x & 0xFFFF) * D + c]);
            const uint4 vB0 = *reinterpret_cast<const uint4*>(&Ybf[(size_t)(rB0.x & 0xFFFF) * D + c]);
            const uint4 vB1 = *reinterpret_cast<const uint4*>(&Ybf[(size_t)(rB1.x & 0xFFFF) * D + c]);
            acc8(accA, wA0, vA0);
            acc8(accA, wA1, vA1);
            acc8(accB, wB0, vB0);
            acc8(accB, wB1, vB1);
            iA += 8;
            iB += 8;
        }

        #pragma unroll
        for (int k = 0; k < 8; ++k) {
            accA[k] += __shfl_xor(accA[k], 16, 64);
            accA[k] += __shfl_xor(accA[k], 32, 64);
            accB[k] += __shfl_xor(accB[k], 16, 64);
            accB[k] += __shfl_xor(accB[k], 32, 64);
        }

        if (lane < 16) {
            if (nodeA < N_NODES) {
                *reinterpret_cast<float4*>(&out[(size_t)nodeA * D + c + 0]) =
                    make_float4(accA[0], accA[1], accA[2], accA[3]);
                *reinterpret_cast<float4*>(&out[(size_t)nodeA * D + c + 4]) =
                    make_float4(accA[4], accA[5], accA[6], accA[7]);
            }
            if (nodeB < N_NODES) {
                *reinterpret_cast<float4*>(&out[(size_t)nodeB * D + c + 0]) =
                    make_float4(accB[0], accB[1], accB[2], accB[3]);
                *reinterpret_cast<float4*>(&out[(size_t)nodeB * D + c + 4]) =
                    make_float4(accB[4], accB[5], accB[6], accB[7]);
            }
        }
    }
}

extern "C" void kernel_launch(void* const* d_in, const int* in_sizes, int n_in,
                              void* d_out, int out_size, void* d_ws, size_t ws_size,
                              hipStream_t stream) {
    const float* node_emb    = (const float*)d_in[0];  // [N, 128]
    const float* edge_weight = (const float*)d_in[1];  // [E]
    const int*   src         = (const int*)d_in[2];    // [E]
    const int*   dst         = (const int*)d_in[3];    // [E]
    const float* W           = (const float*)d_in[4];  // [128, 128]

    float* out = (float*)d_out;

    // Workspace layout (bytes):
    //   Ybf  @ 0          : 12,800,000  (N*128 bf16)
    //   bcur @ 12,800,000 :      3,128  (NBKT ints)
    //   brec @ 12,806,144 : 12,812,288  (NBKT*CAP int2, fixed stride)
    char* ws = (char*)d_ws;
    unsigned short* Ybf  = (unsigned short*)ws;
    int*            bcur = (int*)(ws + 12800000);
    int2*           brec = (int2*)(ws + 12806144);

    (void)hipMemsetAsync(bcur, 0, NBKT * sizeof(int), stream);

    // GEMM (blocks 0..195) runs concurrently with edge scatter (blocks 196..508)
    fused_gemm_scatter<<<GB + NSB, 1024, 0, stream>>>(node_emb, W, src, dst,
                                                      edge_weight, Ybf, bcur, brec);

    // per-bucket in-LDS sort + aggregate (dual-node x 2-unroll gather)
    bucket_agg<<<NBKT, 512, 0, stream>>>(Ybf, brec, bcur, out);
}

// Round 13
// 56.511 us; speedup vs baseline: 1.0430x; 1.0430x over previous
//
#include <hip/hip_runtime.h>

#define N_NODES 50000
#define N_EDGES 640000
#define D 128
#define NBKT 782            // ceil(50000/64) buckets of 64 dst nodes
#define EPB 2048            // edges per scatter block
#define NSB ((N_EDGES + EPB - 1) / EPB)   // 313 scatter blocks
#define GB 196              // gemm super-blocks (4 x 64-row tiles each)
#define CAP 2048            // fixed slot size per bucket (mean 819)

typedef __attribute__((ext_vector_type(8))) short bf16x8;
typedef __attribute__((ext_vector_type(4))) float f32x4;

// round-to-nearest-even f32 -> bf16
static __device__ __forceinline__ unsigned short f2bf(float f) {
    union { float f; unsigned u; } v; v.f = f;
    unsigned r = (v.u + 0x7FFFu + ((v.u >> 16) & 1u)) >> 16;
    return (unsigned short)r;
}

// ---------------------------------------------------------------------------
// Fused kernel: blocks [0, GB) run the MFMA GEMM (Ybf = bf16(X @ W^T));
// blocks [GB, GB+NSB) run the bucketed edge scatter. (Proven rounds 9-10.)
// ---------------------------------------------------------------------------
__global__ __launch_bounds__(1024) void fused_gemm_scatter(
        const float* __restrict__ X, const float* __restrict__ W,
        const int* __restrict__ src, const int* __restrict__ dst,
        const float* __restrict__ ew,
        unsigned short* __restrict__ Ybf,
        int* __restrict__ bcur, int2* __restrict__ brec) {
    __shared__ __align__(16) char smem[32768];
    const int t = threadIdx.x;

    if (blockIdx.x < GB) {
        // ------------------- GEMM branch (4 tiles of 64 rows) -------------------
        unsigned short (*sB)[4][64][8] = (unsigned short (*)[4][64][8])smem;

        for (int idx = t; idx < 2048; idx += 1024) {
            const int ln = idx & 63;
            const int kk = (idx >> 6) & 3;
            const int ct = idx >> 8;
            const int n  = ct * 16 + (ln & 15);
            const int k0 = kk * 32 + (ln >> 4) * 8;
            const float4 wa = *reinterpret_cast<const float4*>(&W[n * D + k0]);
            const float4 wb = *reinterpret_cast<const float4*>(&W[n * D + k0 + 4]);
            unsigned short* d8 = &sB[ct][kk][ln][0];
            d8[0] = f2bf(wa.x); d8[1] = f2bf(wa.y); d8[2] = f2bf(wa.z); d8[3] = f2bf(wa.w);
            d8[4] = f2bf(wb.x); d8[5] = f2bf(wb.y); d8[6] = f2bf(wb.z); d8[7] = f2bf(wb.w);
        }

        const int s    = t >> 8;            // sub-tile 0..3
        const int wv   = (t >> 6) & 3;      // wave within sub-tile
        const int lane = t & 63;
        const int tile = blockIdx.x * 4 + s;
        const int base = tile * 64;

        const int arow = base + wv * 16 + (lane & 15);
        const int grow = min(arow, N_NODES - 1);
        bf16x8 a[4];
        #pragma unroll
        for (int kk = 0; kk < 4; ++kk) {
            const int k0 = kk * 32 + (lane >> 4) * 8;
            const float4 xa = *reinterpret_cast<const float4*>(&X[(size_t)grow * D + k0]);
            const float4 xb = *reinterpret_cast<const float4*>(&X[(size_t)grow * D + k0 + 4]);
            a[kk][0] = (short)f2bf(xa.x); a[kk][1] = (short)f2bf(xa.y);
            a[kk][2] = (short)f2bf(xa.z); a[kk][3] = (short)f2bf(xa.w);
            a[kk][4] = (short)f2bf(xb.x); a[kk][5] = (short)f2bf(xb.y);
            a[kk][6] = (short)f2bf(xb.z); a[kk][7] = (short)f2bf(xb.w);
        }
        __syncthreads();

        f32x4 acc[8];
        #pragma unroll
        for (int ct = 0; ct < 8; ++ct) acc[ct] = (f32x4){0.f, 0.f, 0.f, 0.f};

        #pragma unroll
        for (int ct = 0; ct < 8; ++ct) {
            #pragma unroll
            for (int kk = 0; kk < 4; ++kk) {
                const bf16x8 b = *reinterpret_cast<const bf16x8*>(&sB[ct][kk][lane][0]);
                acc[ct] = __builtin_amdgcn_mfma_f32_16x16x32_bf16(a[kk], b, acc[ct], 0, 0, 0);
            }
        }

        const int orow0 = base + wv * 16 + (lane >> 4) * 4;
        const int ocol  = lane & 15;
        #pragma unroll
        for (int r = 0; r < 4; ++r) {
            const int row = orow0 + r;
            if (row < N_NODES) {
                #pragma unroll
                for (int ct = 0; ct < 8; ++ct)
                    Ybf[(size_t)row * D + ct * 16 + ocol] = f2bf(acc[ct][r]);
            }
        }
    } else {
        // ------------------- Scatter branch (proven round-7/9/10 body) -------------------
        int*  lcnt   = (int*)(smem);            // 784 ints
        int*  loff   = (int*)(smem + 3136);     // 784 ints
        int*  p      = (int*)(smem + 6272);     // 256 ints
        int*  gbase  = (int*)(smem + 7296);     // NBKT ints
        int*  lcur   = (int*)(smem + 10424);    // NBKT ints
        int2* staged = (int2*)(smem + 13552);   // EPB int2 (16 KB)

        const int base = (blockIdx.x - GB) * EPB;
        const int ec = min(EPB, N_EDGES - base);

        for (int i = t; i < 784; i += 1024) lcnt[i] = 0;
        __syncthreads();

        #pragma unroll
        for (int j = 0; j < EPB / 1024; ++j) {
            const int e = base + j * 1024 + t;
            if (e < N_EDGES) atomicAdd(&lcnt[dst[e] >> 6], 1);
        }
        __syncthreads();

        int s0 = 0;
        if (t < 196) s0 = lcnt[4 * t] + lcnt[4 * t + 1] + lcnt[4 * t + 2] + lcnt[4 * t + 3];
        if (t < 256) p[t] = s0;
        __syncthreads();
        for (int off = 1; off < 256; off <<= 1) {
            int add = 0;
            if (t < 256 && t >= off) add = p[t - off];
            __syncthreads();
            if (t < 256) p[t] += add;
            __syncthreads();
        }
        if (t < 196) {
            int b0 = p[t] - s0;
            #pragma unroll
            for (int k = 0; k < 4; ++k) {
                loff[4 * t + k] = b0;
                b0 += lcnt[4 * t + k];
            }
        }
        __syncthreads();

        for (int b = t; b < NBKT; b += 1024) {
            const int c2 = lcnt[b];
            if (c2 > 0) gbase[b] = (b << 11) + atomicAdd(&bcur[b], c2);
            lcur[b] = loff[b];
        }
        __syncthreads();

        #pragma unroll
        for (int j = 0; j < EPB / 1024; ++j) {
            const int e = base + j * 1024 + t;
            if (e < N_EDGES) {
                const int d = dst[e];
                const int b = d >> 6;
                const int pos = atomicAdd(&lcur[b], 1);
                staged[pos] = make_int2((src[e] & 0xFFFF) | ((d & 63) << 16) | (b << 22),
                                        __float_as_int(ew[e]));
            }
        }
        __syncthreads();

        for (int i = t; i < ec; i += 1024) {
            const int2 r = staged[i];
            const int b = ((unsigned)r.x) >> 22;
            const int idx = gbase[b] + (i - loff[b]);
            if (idx < ((b + 1) << 11)) brec[idx] = r;
        }
    }
}

// ---------------------------------------------------------------------------
// bucket_agg: one block per bucket, 512 threads = 8 waves, 2x-unrolled
// gather loop (round-10 version — best measured). Wave w handles nodes
// {w, w+8, ..., w+56}; per 16-lane group g: edges i and i+4 in flight.
// ---------------------------------------------------------------------------
__global__ __launch_bounds__(512) void bucket_agg(const unsigned short* __restrict__ Ybf,
                                                  const int2* __restrict__ brec,
                                                  const int* __restrict__ bcur,
                                                  float* __restrict__ out) {
    __shared__ int  cnts[64];
    __shared__ int  offs[65];
    __shared__ int  cur[64];
    __shared__ int2 sorted[CAP];

    const int t = threadIdx.x;
    const int b = blockIdx.x;
    const int base = b << 11;
    const int cnt = min(bcur[b], CAP);

    if (t < 64) cnts[t] = 0;
    __syncthreads();

    for (int i = t; i < cnt; i += 512)
        atomicAdd(&cnts[(brec[base + i].x >> 16) & 63], 1);
    __syncthreads();

    if (t < 64) {
        int v = cnts[t];
        #pragma unroll
        for (int off = 1; off < 64; off <<= 1) {
            const int u = __shfl_up(v, off, 64);
            if (t >= off) v += u;
        }
        offs[t] = v - cnts[t];
        cur[t]  = v - cnts[t];
        if (t == 63) offs[64] = v;
    }
    __syncthreads();

    for (int i = t; i < cnt; i += 512) {
        const int2 r = brec[base + i];
        const int pos = atomicAdd(&cur[(r.x >> 16) & 63], 1);
        sorted[pos] = r;
    }
    __syncthreads();

    const int wave = t >> 6;          // 0..7
    const int lane = t & 63;
    const int g = lane >> 4;          // edge sub-slot 0..3
    const int c = (lane & 15) * 8;    // 8 output cols

    for (int nl = wave; nl < 64; nl += 8) {
        const int node = b * 64 + nl;
        if (node >= N_NODES) break;
        const int s0 = offs[nl];
        const int s1 = offs[nl + 1];

        float acc[8];
        #pragma unroll
        for (int k = 0; k < 8; ++k) acc[k] = 0.f;

        int i = s0 + g;
        // 2x unrolled: edges i and i+4 in flight together
        for (; i + 4 < s1; i += 8) {
            const int2 r0 = sorted[i];
            const int2 r1 = sorted[i + 4];
            const float w0 = __int_as_float(r0.y);
            const float w1 = __int_as_float(r1.y);
            const uint4 v0 = *reinterpret_cast<const uint4*>(&Ybf[(size_t)(r0.x & 0xFFFF) * D + c]);
            const uint4 v1 = *reinterpret_cast<const uint4*>(&Ybf[(size_t)(r1.x & 0xFFFF) * D + c]);
            acc[0] += w0 * __uint_as_float(v0.x << 16);
            acc[1] += w0 * __uint_as_float(v0.x & 0xFFFF0000u);
            acc[2] += w0 * __uint_as_float(v0.y << 16);
            acc[3] += w0 * __uint_as_float(v0.y & 0xFFFF0000u);
            acc[4] += w0 * __uint_as_float(v0.z << 16);
            acc[5] += w0 * __uint_as_float(v0.z & 0xFFFF0000u);
            acc[6] += w0 * __uint_as_float(v0.w << 16);
            acc[7] += w0 * __uint_as_float(v0.w & 0xFFFF0000u);
            acc[0] += w1 * __uint_as_float(v1.x << 16);
            acc[1] += w1 * __uint_as_float(v1.x & 0xFFFF0000u);
            acc[2] += w1 * __uint_as_float(v1.y << 16);
            acc[3] += w1 * __uint_as_float(v1.y & 0xFFFF0000u);
            acc[4] += w1 * __uint_as_float(v1.z << 16);
            acc[5] += w1 * __uint_as_float(v1.z & 0xFFFF0000u);
            acc[6] += w1 * __uint_as_float(v1.w << 16);
            acc[7] += w1 * __uint_as_float(v1.w & 0xFFFF0000u);
        }
        if (i < s1) {
            const int2 r = sorted[i];
            const float w = __int_as_float(r.y);
            const uint4 v = *reinterpret_cast<const uint4*>(&Ybf[(size_t)(r.x & 0xFFFF) * D + c]);
            acc[0] += w * __uint_as_float(v.x << 16);
            acc[1] += w * __uint_as_float(v.x & 0xFFFF0000u);
            acc[2] += w * __uint_as_float(v.y << 16);
            acc[3] += w * __uint_as_float(v.y & 0xFFFF0000u);
            acc[4] += w * __uint_as_float(v.z << 16);
            acc[5] += w * __uint_as_float(v.z & 0xFFFF0000u);
            acc[6] += w * __uint_as_float(v.w << 16);
            acc[7] += w * __uint_as_float(v.w & 0xFFFF0000u);
        }

        #pragma unroll
        for (int k = 0; k < 8; ++k) {
            acc[k] += __shfl_xor(acc[k], 16, 64);
            acc[k] += __shfl_xor(acc[k], 32, 64);
        }

        if (lane < 16) {
            *reinterpret_cast<float4*>(&out[(size_t)node * D + c + 0]) =
                make_float4(acc[0], acc[1], acc[2], acc[3]);
            *reinterpret_cast<float4*>(&out[(size_t)node * D + c + 4]) =
                make_float4(acc[4], acc[5], acc[6], acc[7]);
        }
    }
}

extern "C" void kernel_launch(void* const* d_in, const int* in_sizes, int n_in,
                              void* d_out, int out_size, void* d_ws, size_t ws_size,
                              hipStream_t stream) {
    const float* node_emb    = (const float*)d_in[0];  // [N, 128]
    const float* edge_weight = (const float*)d_in[1];  // [E]
    const int*   src         = (const int*)d_in[2];    // [E]
    const int*   dst         = (const int*)d_in[3];    // [E]
    const float* W           = (const float*)d_in[4];  // [128, 128]

    float* out = (float*)d_out;

    // Workspace layout (bytes):
    //   Ybf  @ 0          : 12,800,000  (N*128 bf16)
    //   bcur @ 12,800,000 :      3,128  (NBKT ints)
    //   brec @ 12,806,144 : 12,812,288  (NBKT*CAP int2, fixed stride)
    char* ws = (char*)d_ws;
    unsigned short* Ybf  = (unsigned short*)ws;
    int*            bcur = (int*)(ws + 12800000);
    int2*           brec = (int2*)(ws + 12806144);

    (void)hipMemsetAsync(bcur, 0, NBKT * sizeof(int), stream);

    // GEMM (blocks 0..195) runs concurrently with edge scatter (blocks 196..508)
    fused_gemm_scatter<<<GB + NSB, 1024, 0, stream>>>(node_emb, W, src, dst,
                                                      edge_weight, Ybf, bcur, brec);

    // per-bucket in-LDS sort + aggregate (8 waves, 2x-unrolled gather)
    bucket_agg<<<NBKT, 512, 0, stream>>>(Ybf, brec, bcur, out);
}